// Round 1
// baseline (308.984 us; speedup 1.0000x reference)
//
#include <hip/hip_runtime.h>
#include <hip/hip_bf16.h>

// ConvCaps EM-routing, fp32.
// P=900 parents (30x30), N=144 children (3x3 kernel x 16 in-caps), C=32 out-caps.
// Votes recomputed on the fly (4x4 matmul per (p,n,c)); rr/zz buffer in ws.

#define S_IN   32
#define S_OUT  30
#define KSZ    3
#define C_IN   16
#define C_OUTC 32
#define PP     (S_OUT * S_OUT)     // 900
#define NN     (KSZ * KSZ * C_IN)  // 144
#define EPSF   1e-7f

// ---------------------------------------------------------------------------
// M-step: one block per parent p. 256 threads = 8 n-slots x 32 c.
// Computes rs, mean, var over n, then costs -> activation.
// FIRST: rr == 1/32 constant.  LAST: write act+pose to d_out instead of ws.
// ---------------------------------------------------------------------------
template <bool FIRST, bool LAST>
__global__ __launch_bounds__(256) void mstep_kernel(
    const float* __restrict__ pose,    // [S_IN^2, C_IN, 16]
    const float* __restrict__ W,       // [N, C, 16]
    const float* __restrict__ beta_a,  // [C]
    const float* __restrict__ beta_v,  // [C]
    const float* __restrict__ rr,      // [P, N, C]
    float* __restrict__ meanw,         // [P, C, 16]
    float* __restrict__ i2vw,          // [P, C, 16]
    float* __restrict__ basew,         // [P, C]  = log(act+eps) + prob_main
    float* __restrict__ out,           // d_out (LAST only)
    float lambd)
{
    const int p = blockIdx.x;
    const int t = threadIdx.x;
    const int c = t & 31;
    const int slot = t >> 5;  // 0..7

    __shared__ float pose_s[NN * 16];      // 2304 floats = 9.2 KB
    __shared__ float red[33 * 8 * 32];     // 33.8 KB

    const int prow = p / S_OUT, pcol = p % S_OUT;
    // Stage gathered child poses: idx = kk*256 + ci*16 + ij (contiguous per kk).
    for (int idx = t; idx < NN * 16; idx += 256) {
        int kk = idx >> 8;
        int child = (prow + kk / 3) * S_IN + (pcol + kk % 3);
        pose_s[idx] = pose[child * 256 + (idx & 255)];
    }
    __syncthreads();

    float rsum = 0.f;
    float s1[16], s2[16];
#pragma unroll
    for (int q = 0; q < 16; ++q) { s1[q] = 0.f; s2[q] = 0.f; }

    for (int n = slot; n < NN; n += 8) {
        float r = FIRST ? (1.0f / 32.0f) : rr[(p * NN + n) * 32 + c];
        float po[16], w[16];
        const float* ps = &pose_s[n * 16];
        const float* wn = &W[(n * 32 + c) * 16];
#pragma unroll
        for (int q = 0; q < 16; ++q) { po[q] = ps[q]; w[q] = wn[q]; }
#pragma unroll
        for (int i = 0; i < 4; ++i) {
#pragma unroll
            for (int j = 0; j < 4; ++j) {
                float v = po[i * 4 + 0] * w[0 * 4 + j] + po[i * 4 + 1] * w[1 * 4 + j] +
                          po[i * 4 + 2] * w[2 * 4 + j] + po[i * 4 + 3] * w[3 * 4 + j];
                int ij = i * 4 + j;
                s1[ij] += r * v;
                s2[ij] += r * v * v;
            }
        }
        rsum += r;
    }

    // Cross-slot reduction in LDS: red[q][slot][c]
#pragma unroll
    for (int q = 0; q < 16; ++q) red[(q * 8 + slot) * 32 + c] = s1[q];
#pragma unroll
    for (int q = 0; q < 16; ++q) red[((16 + q) * 8 + slot) * 32 + c] = s2[q];
    red[(32 * 8 + slot) * 32 + c] = rsum;
    __syncthreads();
    for (int off = 4; off >= 1; off >>= 1) {
        if (slot < off) {
#pragma unroll
            for (int q = 0; q < 33; ++q)
                red[(q * 8 + slot) * 32 + c] += red[(q * 8 + slot + off) * 32 + c];
        }
        __syncthreads();
    }

    if (slot == 0) {  // threads 0..31, c = t
        float rs = red[(32 * 8) * 32 + c];
        float inv_rs = 1.0f / rs;
        float logstd_sum = 0.f;
        float mean[16], i2v[16];
#pragma unroll
        for (int q = 0; q < 16; ++q) {
            float m = red[(q * 8) * 32 + c] * inv_rs;
            float var = red[((16 + q) * 8) * 32 + c] * inv_rs - m * m;
            var = fmaxf(var, 0.f);
            float sd = sqrtf(var);
            mean[q] = m;
            i2v[q] = 0.5f / var;
            logstd_sum += logf(sd + EPSF);
        }
        float sumcosts = 16.f * beta_v[c] + rs * logstd_sum;
        float a = 1.0f / (1.0f + expf(-(lambd * (beta_a[c] - sumcosts))));
        if (LAST) {
            out[p * 32 + c] = a;
#pragma unroll
            for (int q = 0; q < 16; ++q)
                out[PP * 32 + (p * 32 + c) * 16 + q] = mean[q];
        } else {
            basew[p * 32 + c] = logf(a + EPSF) - logstd_sum;
#pragma unroll
            for (int q = 0; q < 16; ++q) {
                meanw[(p * 32 + c) * 16 + q] = mean[q];
                i2vw[(p * 32 + c) * 16 + q] = i2v[q];
            }
        }
    }
}

// ---------------------------------------------------------------------------
// E-step part 1: zz[p,n,c] = base[p,c] - sum_ij (v - mean)^2 * i2v
// Block: one p, 8 n's. 256 threads = 8 n x 32 c.
// ---------------------------------------------------------------------------
__global__ __launch_bounds__(256) void estep_kernel(
    const float* __restrict__ pose, const float* __restrict__ W,
    const float* __restrict__ meanw, const float* __restrict__ i2vw,
    const float* __restrict__ basew, float* __restrict__ zz)
{
    const int b = blockIdx.x;  // 900*18
    const int p = b / 18, chunk = b % 18;
    const int t = threadIdx.x;
    const int c = t & 31;
    const int slot = t >> 5;
    const int n = chunk * 8 + slot;

    __shared__ float pose_s[8 * 16];
    const int prow = p / S_OUT, pcol = p % S_OUT;
    if (t < 128) {
        int nn = chunk * 8 + (t >> 4);
        int kk = nn >> 4, ci = nn & 15;
        int child = (prow + kk / 3) * S_IN + (pcol + kk % 3);
        pose_s[t] = pose[child * 256 + ci * 16 + (t & 15)];
    }
    __syncthreads();

    const float* ps = &pose_s[slot * 16];
    const float* wn = &W[(n * 32 + c) * 16];
    const float* mn = &meanw[(p * 32 + c) * 16];
    const float* iv = &i2vw[(p * 32 + c) * 16];
    float pe = 0.f;
#pragma unroll
    for (int i = 0; i < 4; ++i) {
#pragma unroll
        for (int j = 0; j < 4; ++j) {
            float v = ps[i * 4 + 0] * wn[0 * 4 + j] + ps[i * 4 + 1] * wn[1 * 4 + j] +
                      ps[i * 4 + 2] * wn[2 * 4 + j] + ps[i * 4 + 3] * wn[3 * 4 + j];
            float d = v - mn[i * 4 + j];
            pe += d * d * iv[i * 4 + j];
        }
    }
    zz[(p * NN + n) * 32 + c] = basew[p * 32 + c] - pe;
}

// ---------------------------------------------------------------------------
// E-step part 2: column (over p) max and sum(exp) per (n,c).
// Block: one n. 256 threads = 8 p-slots x 32 c.
// ---------------------------------------------------------------------------
__global__ __launch_bounds__(256) void colreduce_kernel(
    const float* __restrict__ zz, float* __restrict__ colmax,
    float* __restrict__ colsum)
{
    const int n = blockIdx.x;  // 144
    const int t = threadIdx.x;
    const int c = t & 31;
    const int slot = t >> 5;

    __shared__ float redm[8 * 32];
    __shared__ float reds[8 * 32];

    float m = -1e30f;
    for (int p = slot; p < PP; p += 8) m = fmaxf(m, zz[(p * NN + n) * 32 + c]);
    redm[slot * 32 + c] = m;
    __syncthreads();
    for (int off = 4; off >= 1; off >>= 1) {
        if (slot < off)
            redm[slot * 32 + c] = fmaxf(redm[slot * 32 + c], redm[(slot + off) * 32 + c]);
        __syncthreads();
    }
    m = redm[c];

    float s = 0.f;
    for (int p = slot; p < PP; p += 8) s += expf(zz[(p * NN + n) * 32 + c] - m);
    reds[slot * 32 + c] = s;
    __syncthreads();
    for (int off = 4; off >= 1; off >>= 1) {
        if (slot < off) reds[slot * 32 + c] += reds[(slot + off) * 32 + c];
        __syncthreads();
    }
    if (slot == 0) {
        colmax[n * 32 + c] = m;
        colsum[n * 32 + c] = reds[c];
    }
}

// ---------------------------------------------------------------------------
// E-step part 3: rr = exp(zz - colmax) / colsum   (in place)
// ---------------------------------------------------------------------------
__global__ __launch_bounds__(256) void normalize_kernel(
    float* __restrict__ zz, const float* __restrict__ colmax,
    const float* __restrict__ colsum)
{
    const int idx = blockIdx.x * 256 + threadIdx.x;
    if (idx >= PP * NN * 32) return;
    const int nc = idx % (NN * 32);
    zz[idx] = expf(zz[idx] - colmax[nc]) / colsum[nc];
}

extern "C" void kernel_launch(void* const* d_in, const int* in_sizes, int n_in,
                              void* d_out, int out_size, void* d_ws, size_t ws_size,
                              hipStream_t stream) {
    const float* pose   = (const float*)d_in[1];  // input_act (d_in[0]) is unused
    const float* W      = (const float*)d_in[2];
    const float* beta_a = (const float*)d_in[3];
    const float* beta_v = (const float*)d_in[4];
    float* out = (float*)d_out;
    float* ws = (float*)d_ws;

    float* rrbuf  = ws;                    // P*N*C = 4,147,200
    float* meanw  = rrbuf + PP * NN * 32;  // P*C*16 = 460,800
    float* i2vw   = meanw + PP * 32 * 16;  // 460,800
    float* basew  = i2vw + PP * 32 * 16;   // P*C = 28,800
    float* colmax = basew + PP * 32;       // N*C = 4,608
    float* colsum = colmax + NN * 32;      // 4,608

    const float lambd0 = 0.0f;
    const float lambd1 = 0.01f * (1.0f - 0.95f);
    const float lambd2 = 0.01f * (1.0f - 0.95f * 0.95f);

    const int eg = PP * 18;                 // estep grid
    const int ng = (PP * NN * 32) / 256;    // normalize grid (exact)

    // i = 0
    mstep_kernel<true, false><<<PP, 256, 0, stream>>>(
        pose, W, beta_a, beta_v, rrbuf, meanw, i2vw, basew, out, lambd0);
    estep_kernel<<<eg, 256, 0, stream>>>(pose, W, meanw, i2vw, basew, rrbuf);
    colreduce_kernel<<<NN, 256, 0, stream>>>(rrbuf, colmax, colsum);
    normalize_kernel<<<ng, 256, 0, stream>>>(rrbuf, colmax, colsum);
    // i = 1
    mstep_kernel<false, false><<<PP, 256, 0, stream>>>(
        pose, W, beta_a, beta_v, rrbuf, meanw, i2vw, basew, out, lambd1);
    estep_kernel<<<eg, 256, 0, stream>>>(pose, W, meanw, i2vw, basew, rrbuf);
    colreduce_kernel<<<NN, 256, 0, stream>>>(rrbuf, colmax, colsum);
    normalize_kernel<<<ng, 256, 0, stream>>>(rrbuf, colmax, colsum);
    // i = 2 (final)
    mstep_kernel<false, true><<<PP, 256, 0, stream>>>(
        pose, W, beta_a, beta_v, rrbuf, meanw, i2vw, basew, out, lambd2);
}

// Round 2
// 169.056 us; speedup vs baseline: 1.8277x; 1.8277x over previous
//
#include <hip/hip_runtime.h>
#include <hip/hip_bf16.h>

// ConvCaps EM-routing, fp32.
// P=900 parents (30x30), N=144 children (3x3 kernel x 16 in-caps), C=32 out-caps.
// Pipeline per routing iter: mstep (fused rr=exp(zz-shift)) -> estep (fused
// per-chunk softmax partials) -> combine (shift = colmax + log(colsum)).

#define S_IN   32
#define S_OUT  30
#define KSZ    3
#define C_IN   16
#define PP     (S_OUT * S_OUT)     // 900
#define NN     (KSZ * KSZ * C_IN)  // 144
#define NCH    15                  // p-chunks in estep
#define PCH    60                  // parents per chunk (15*60 = 900)
#define EPSF   1e-7f

// ---------------------------------------------------------------------------
// M-step: one block per parent p. 256 threads = 8 n-slots x 32 c.
// FIRST: rr == 1/32.  Else rr = exp(zz - shift[n,c]) computed on the fly.
// LAST: write act+pose to d_out.
// ---------------------------------------------------------------------------
template <bool FIRST, bool LAST>
__global__ __launch_bounds__(256) void mstep_kernel(
    const float* __restrict__ pose,    // [S_IN^2, C_IN, 16]
    const float* __restrict__ W,       // [N, C, 16]
    const float* __restrict__ beta_a,  // [C]
    const float* __restrict__ beta_v,  // [C]
    const float* __restrict__ zz,      // [P, N, C]
    const float* __restrict__ shift,   // [N, C]
    float* __restrict__ meanw,         // [P, C, 16]
    float* __restrict__ i2vw,          // [P, C, 16]
    float* __restrict__ basew,         // [P, C]
    float* __restrict__ out,           // d_out (LAST only)
    float lambd)
{
    const int p = blockIdx.x;
    const int t = threadIdx.x;
    const int c = t & 31;
    const int slot = t >> 5;   // 0..7
    const int wave = t >> 6;   // 0..3

    __shared__ float pose_s[NN * 16];        // 9.2 KB
    __shared__ float red[33 * 4 * 32];       // 16.9 KB

    const int prow = p / S_OUT, pcol = p % S_OUT;
    for (int idx = t; idx < NN * 16; idx += 256) {
        int kk = idx >> 8;
        int child = (prow + kk / 3) * S_IN + (pcol + kk % 3);
        pose_s[idx] = pose[child * 256 + (idx & 255)];
    }
    __syncthreads();

    float rsum = 0.f;
    float s1[16], s2[16];
#pragma unroll
    for (int q = 0; q < 16; ++q) { s1[q] = 0.f; s2[q] = 0.f; }

    for (int n = slot; n < NN; n += 8) {
        float r;
        if (FIRST) r = 1.0f / 32.0f;
        else       r = __expf(zz[(p * NN + n) * 32 + c] - shift[n * 32 + c]);
        float po[16], w[16];
        const float* ps = &pose_s[n * 16];
        const float4* wn = (const float4*)&W[(n * 32 + c) * 16];
#pragma unroll
        for (int q = 0; q < 4; ++q) {
            float4 wv = wn[q];
            w[q * 4 + 0] = wv.x; w[q * 4 + 1] = wv.y;
            w[q * 4 + 2] = wv.z; w[q * 4 + 3] = wv.w;
        }
#pragma unroll
        for (int q = 0; q < 16; ++q) po[q] = ps[q];
#pragma unroll
        for (int i = 0; i < 4; ++i) {
#pragma unroll
            for (int j = 0; j < 4; ++j) {
                float v = po[i * 4 + 0] * w[0 * 4 + j] + po[i * 4 + 1] * w[1 * 4 + j] +
                          po[i * 4 + 2] * w[2 * 4 + j] + po[i * 4 + 3] * w[3 * 4 + j];
                int ij = i * 4 + j;
                s1[ij] += r * v;
                s2[ij] += r * v * v;
            }
        }
        rsum += r;
    }

    // slot-pair reduce within wave (slots 2w and 2w+1 are lane halves)
#pragma unroll
    for (int q = 0; q < 16; ++q) {
        s1[q] += __shfl_xor(s1[q], 32);
        s2[q] += __shfl_xor(s2[q], 32);
    }
    rsum += __shfl_xor(rsum, 32);

    if ((t & 32) == 0) {
#pragma unroll
        for (int q = 0; q < 16; ++q) {
            red[(q * 4 + wave) * 32 + c] = s1[q];
            red[((16 + q) * 4 + wave) * 32 + c] = s2[q];
        }
        red[(32 * 4 + wave) * 32 + c] = rsum;
    }
    __syncthreads();

    if (t < 32) {  // c = t
        float rs = 0.f;
#pragma unroll
        for (int w = 0; w < 4; ++w) rs += red[(32 * 4 + w) * 32 + c];
        float inv_rs = 1.0f / rs;
        float logstd_sum = 0.f;
        float mean[16], i2v[16];
#pragma unroll
        for (int q = 0; q < 16; ++q) {
            float a1 = 0.f, a2 = 0.f;
#pragma unroll
            for (int w = 0; w < 4; ++w) {
                a1 += red[(q * 4 + w) * 32 + c];
                a2 += red[((16 + q) * 4 + w) * 32 + c];
            }
            float m = a1 * inv_rs;
            float var = a2 * inv_rs - m * m;
            var = fmaxf(var, 1e-30f);
            float sd = __builtin_sqrtf(var);
            mean[q] = m;
            i2v[q] = 0.5f / var;
            logstd_sum += __logf(sd + EPSF);
        }
        float sumcosts = 16.f * beta_v[c] + rs * logstd_sum;
        float a = 1.0f / (1.0f + __expf(-(lambd * (beta_a[c] - sumcosts))));
        if (LAST) {
            out[p * 32 + c] = a;
#pragma unroll
            for (int q = 0; q < 16; ++q)
                out[PP * 32 + (p * 32 + c) * 16 + q] = mean[q];
        } else {
            basew[p * 32 + c] = __logf(a + EPSF) - logstd_sum;
#pragma unroll
            for (int q = 0; q < 16; ++q) {
                meanw[(p * 32 + c) * 16 + q] = mean[q];
                i2vw[(p * 32 + c) * 16 + q] = i2v[q];
            }
        }
    }
}

// ---------------------------------------------------------------------------
// E-step fused: block = (chunk, n). 256 threads = 8 p-slots x 32 c, each slot
// covers up to 8 parents (60 per chunk). W[n,c,:] held in registers across
// the whole chunk. Writes zz and per-chunk softmax partials (max, sum-exp).
// ---------------------------------------------------------------------------
__global__ __launch_bounds__(256) void estep_kernel(
    const float* __restrict__ pose, const float* __restrict__ W,
    const float* __restrict__ meanw, const float* __restrict__ i2vw,
    const float* __restrict__ basew, float* __restrict__ zz,
    float* __restrict__ pmaxg,   // [NCH, N, C]
    float* __restrict__ psumg)   // [NCH, N, C]
{
    const int b = blockIdx.x;          // 15*144; consecutive b -> same chunk
    const int n = b % NN;
    const int chunk = b / NN;
    const int t = threadIdx.x;
    const int c = t & 31;
    const int ps = t >> 5;
    const int pbase = chunk * PCH;

    __shared__ float pose_s[PCH * 16];   // 3.75 KB
    __shared__ float redm[8 * 32];
    __shared__ float reds[8 * 32];
    __shared__ float bmax[32];

    const int kk = n >> 4, ci = n & 15;
    const int kr = kk / 3, kc = kk % 3;
    for (int idx = t; idx < PCH * 16; idx += 256) {
        int pi = idx >> 4, q = idx & 15;
        int p = pbase + pi;
        int child = (p / S_OUT + kr) * S_IN + (p % S_OUT + kc);
        pose_s[idx] = pose[child * 256 + ci * 16 + q];
    }

    float w[16];
    {
        const float4* wn = (const float4*)&W[(n * 32 + c) * 16];
#pragma unroll
        for (int q = 0; q < 4; ++q) {
            float4 wv = wn[q];
            w[q * 4 + 0] = wv.x; w[q * 4 + 1] = wv.y;
            w[q * 4 + 2] = wv.z; w[q * 4 + 3] = wv.w;
        }
    }
    __syncthreads();

    float zl[8];
    float vmax = -1e30f;
#pragma unroll
    for (int kp = 0; kp < 8; ++kp) {
        int pi = ps * 8 + kp;
        if (pi < PCH) {
            int p = pbase + pi;
            const float4* mn4 = (const float4*)&meanw[(p * 32 + c) * 16];
            const float4* iv4 = (const float4*)&i2vw[(p * 32 + c) * 16];
            float mn[16], iv[16];
#pragma unroll
            for (int q = 0; q < 4; ++q) {
                float4 mv = mn4[q], vv = iv4[q];
                mn[q * 4 + 0] = mv.x; mn[q * 4 + 1] = mv.y;
                mn[q * 4 + 2] = mv.z; mn[q * 4 + 3] = mv.w;
                iv[q * 4 + 0] = vv.x; iv[q * 4 + 1] = vv.y;
                iv[q * 4 + 2] = vv.z; iv[q * 4 + 3] = vv.w;
            }
            const float* po = &pose_s[pi * 16];
            float pe = 0.f;
#pragma unroll
            for (int i = 0; i < 4; ++i) {
#pragma unroll
                for (int j = 0; j < 4; ++j) {
                    float v = po[i * 4 + 0] * w[0 * 4 + j] + po[i * 4 + 1] * w[1 * 4 + j] +
                              po[i * 4 + 2] * w[2 * 4 + j] + po[i * 4 + 3] * w[3 * 4 + j];
                    float d = v - mn[i * 4 + j];
                    pe += d * d * iv[i * 4 + j];
                }
            }
            float zzv = basew[p * 32 + c] - pe;
            zz[(p * NN + n) * 32 + c] = zzv;
            zl[kp] = zzv;
            vmax = fmaxf(vmax, zzv);
        } else {
            zl[kp] = -1e30f;
        }
    }

    redm[ps * 32 + c] = vmax;
    __syncthreads();
    if (t < 32) {
        float m = redm[c];
#pragma unroll
        for (int s = 1; s < 8; ++s) m = fmaxf(m, redm[s * 32 + c]);
        bmax[c] = m;
    }
    __syncthreads();
    const float m = bmax[c];

    float ss = 0.f;
#pragma unroll
    for (int kp = 0; kp < 8; ++kp) {
        int pi = ps * 8 + kp;
        if (pi < PCH) ss += __expf(zl[kp] - m);
    }
    reds[ps * 32 + c] = ss;
    __syncthreads();
    if (t < 32) {
        float s = 0.f;
#pragma unroll
        for (int sl = 0; sl < 8; ++sl) s += reds[sl * 32 + c];
        pmaxg[(chunk * NN + n) * 32 + c] = m;
        psumg[(chunk * NN + n) * 32 + c] = s;
    }
}

// ---------------------------------------------------------------------------
// Combine chunk partials: shift[n,c] = colmax + log(colsum).
// ---------------------------------------------------------------------------
__global__ __launch_bounds__(256) void combine_kernel(
    const float* __restrict__ pmaxg, const float* __restrict__ psumg,
    float* __restrict__ shift)
{
    const int idx = blockIdx.x * 256 + threadIdx.x;
    if (idx >= NN * 32) return;
    float m = -1e30f;
#pragma unroll
    for (int ch = 0; ch < NCH; ++ch) m = fmaxf(m, pmaxg[ch * NN * 32 + idx]);
    float s = 0.f;
#pragma unroll
    for (int ch = 0; ch < NCH; ++ch)
        s += psumg[ch * NN * 32 + idx] * __expf(pmaxg[ch * NN * 32 + idx] - m);
    shift[idx] = m + __logf(s);
}

extern "C" void kernel_launch(void* const* d_in, const int* in_sizes, int n_in,
                              void* d_out, int out_size, void* d_ws, size_t ws_size,
                              hipStream_t stream) {
    const float* pose   = (const float*)d_in[1];  // input_act (d_in[0]) is unused
    const float* W      = (const float*)d_in[2];
    const float* beta_a = (const float*)d_in[3];
    const float* beta_v = (const float*)d_in[4];
    float* out = (float*)d_out;
    float* ws = (float*)d_ws;

    float* zzbuf  = ws;                     // P*N*C = 4,147,200
    float* meanw  = zzbuf + PP * NN * 32;   // 460,800
    float* i2vw   = meanw + PP * 32 * 16;   // 460,800
    float* basew  = i2vw + PP * 32 * 16;    // 28,800
    float* pmaxg  = basew + PP * 32;        // 69,120
    float* psumg  = pmaxg + NCH * NN * 32;  // 69,120
    float* shiftb = psumg + NCH * NN * 32;  // 4,608

    const float lambd0 = 0.0f;
    const float lambd1 = 0.01f * (1.0f - 0.95f);
    const float lambd2 = 0.01f * (1.0f - 0.95f * 0.95f);

    const int eg = NCH * NN;  // 2160 blocks
    const int cg = (NN * 32 + 255) / 256;  // 18 blocks

    // i = 0
    mstep_kernel<true, false><<<PP, 256, 0, stream>>>(
        pose, W, beta_a, beta_v, zzbuf, shiftb, meanw, i2vw, basew, out, lambd0);
    estep_kernel<<<eg, 256, 0, stream>>>(pose, W, meanw, i2vw, basew, zzbuf, pmaxg, psumg);
    combine_kernel<<<cg, 256, 0, stream>>>(pmaxg, psumg, shiftb);
    // i = 1
    mstep_kernel<false, false><<<PP, 256, 0, stream>>>(
        pose, W, beta_a, beta_v, zzbuf, shiftb, meanw, i2vw, basew, out, lambd1);
    estep_kernel<<<eg, 256, 0, stream>>>(pose, W, meanw, i2vw, basew, zzbuf, pmaxg, psumg);
    combine_kernel<<<cg, 256, 0, stream>>>(pmaxg, psumg, shiftb);
    // i = 2 (final)
    mstep_kernel<false, true><<<PP, 256, 0, stream>>>(
        pose, W, beta_a, beta_v, zzbuf, shiftb, meanw, i2vw, basew, out, lambd2);
}